// Round 3
// baseline (101.526 us; speedup 1.0000x reference)
//
#include <hip/hip_runtime.h>

#define HD  16    // hidden_dim
#define DIM 256   // query dim
#define NW  65    // 4*HD+1 weights per box
#define HW  64    // grid H=W

typedef float f32x4_t __attribute__((ext_vector_type(4)));

// One block per box n:
//   phase 1: weights = q @ Wg + bg, parallelized: 4 threads per output j
//            (64-deep FMA chains, shfl_xor 4-lane reduce)
//   phase 2: render 64x64; thread owns 4 consecutive x, 4 row-iterations.
//            pre = fmaf(rx, w1x[k], ayb[k]) -> 3 VALU ops per (pixel,k).
__global__ __launch_bounds__(256, 4) void posmlp_kernel(
    const float* __restrict__ pos,      // (N,4)
    const float* __restrict__ queries,  // (N,DIM)
    const float* __restrict__ Wg,       // (DIM,NW)
    const float* __restrict__ bg,       // (NW)
    float* __restrict__ out)            // (N,HW,HW)
{
    const int n   = blockIdx.x;
    const int tid = threadIdx.x;

    __shared__ float qs[DIM];
    __shared__ float wl[NW];

    qs[tid] = queries[n * DIM + tid];
    __syncthreads();

    // ---- phase 1: wl[j] = bg[j] + sum_d qs[d]*Wg[d,j], 4 threads per j ----
    {
        const int j    = tid >> 2;   // 0..63
        const int part = tid & 3;    // 0..3, sums d = part*64 .. part*64+63
        float a = 0.f;
        #pragma unroll 8
        for (int i = 0; i < 64; ++i) {
            const int d = part * 64 + i;
            a = fmaf(qs[d], Wg[d * NW + j], a);
        }
        a += __shfl_xor(a, 1);
        a += __shfl_xor(a, 2);
        if (part == 0) wl[j] = a + bg[j];

        if (tid < 4) {               // j = 64 (b2) tail, 4 threads
            float b = 0.f;
            #pragma unroll 8
            for (int i = 0; i < 64; ++i) {
                const int d = tid * 64 + i;
                b = fmaf(qs[d], Wg[d * NW + 64], b);
            }
            b += __shfl_xor(b, 1);
            b += __shfl_xor(b, 2);
            if (tid == 0) wl[64] = b + bg[64];
        }
    }
    __syncthreads();

    // ---- phase 2: render ----
    const float cx = pos[n * 4 + 0];
    const float cy = pos[n * 4 + 1];
    const float inv_bw = 1.0f / pos[n * 4 + 2];
    const float inv_bh = 1.0f / pos[n * 4 + 3];

    float w1x[HD], w1y[HD], b1[HD], w2[HD];
    #pragma unroll
    for (int k = 0; k < HD; ++k) {
        w1x[k] = wl[k];
        w1y[k] = wl[HD + k];
        b1[k]  = wl[2 * HD + k];
        w2[k]  = wl[3 * HD + k];
    }
    const float b2 = wl[4 * HD];

    const int xg = tid & 15;   // x-group: owns x0..x0+3
    const int yl = tid >> 4;   // 0..15
    const int x0 = xg * 4;

    float rx[4];
    #pragma unroll
    for (int j = 0; j < 4; ++j)
        rx[j] = ((x0 + j + 0.5f) * (1.0f / HW) - cx) * inv_bw;

    float* outn = out + (size_t)n * (HW * HW);

    #pragma unroll
    for (int it = 0; it < 4; ++it) {
        const int y = it * 16 + yl;
        const float ry = ((y + 0.5f) * (1.0f / HW) - cy) * inv_bh;

        float ayb[HD];
        #pragma unroll
        for (int k = 0; k < HD; ++k)
            ayb[k] = fmaf(ry, w1y[k], b1[k]);

        f32x4_t acc = { b2, b2, b2, b2 };
        #pragma unroll
        for (int k = 0; k < HD; ++k) {
            const float t0 = fmaxf(fmaf(rx[0], w1x[k], ayb[k]), 0.0f);
            const float t1 = fmaxf(fmaf(rx[1], w1x[k], ayb[k]), 0.0f);
            const float t2 = fmaxf(fmaf(rx[2], w1x[k], ayb[k]), 0.0f);
            const float t3 = fmaxf(fmaf(rx[3], w1x[k], ayb[k]), 0.0f);
            acc.x = fmaf(t0, w2[k], acc.x);
            acc.y = fmaf(t1, w2[k], acc.y);
            acc.z = fmaf(t2, w2[k], acc.z);
            acc.w = fmaf(t3, w2[k], acc.w);
        }
        // streaming store: 39.3 MB written once, never re-read by us
        __builtin_nontemporal_store(acc, (f32x4_t*)(outn + y * HW + x0));
    }
}

extern "C" void kernel_launch(void* const* d_in, const int* in_sizes, int n_in,
                              void* d_out, int out_size, void* d_ws, size_t ws_size,
                              hipStream_t stream) {
    const float* pos = (const float*)d_in[0];
    const float* q   = (const float*)d_in[1];
    const float* Wg  = (const float*)d_in[2];
    const float* bg  = (const float*)d_in[3];
    float* out = (float*)d_out;

    const int N = in_sizes[0] / 4;   // 8*300 = 2400 boxes
    posmlp_kernel<<<N, 256, 0, stream>>>(pos, q, Wg, bg, out);
}